// Round 1
// baseline (902.043 us; speedup 1.0000x reference)
//
#include <hip/hip_runtime.h>

// EUNN: 256 layers; each layer = rotation on even pairs (2i,2i+1), then
// rotation on odd pairs (2i+1,2i+2 mod H).
// Pair math: y0 = e^{i*phi} (ct*u - st*v); y1 = st*u + ct*v.

#define H_DIM 1024
#define C2 256
#define RPW 2   // batch rows per wave

// coef layout: [c][phase][j][lane] as float4 (ct, st, cp, sp), pair i = 8*lane + j
// -> flat float4 index: ((c*2 + phase)*8 + j)*64 + lane,  4 MB total.

__global__ __launch_bounds__(256) void eunn_coef_kernel(
    const float* __restrict__ phi0, const float* __restrict__ theta0,
    const float* __restrict__ phi1, const float* __restrict__ theta1,
    float4* __restrict__ coef) {
    int t = blockIdx.x * 256 + threadIdx.x;     // [0, 256*2*512)
    int i = t & 511;                            // pair index
    int p = (t >> 9) & 1;                       // phase (0: even pairs, 1: odd pairs)
    int c = t >> 10;                            // layer
    const float* phi   = p ? phi1   : phi0;
    const float* theta = p ? theta1 : theta0;
    float ph = phi[i * C2 + c];
    float th = theta[i * C2 + c];
    float sp, cp, st, ct;
    __sincosf(ph, &sp, &cp);
    __sincosf(th, &st, &ct);
    int j = i & 7;
    int l = i >> 3;
    coef[(((c * 2 + p) * 8) + j) * 64 + l] = make_float4(ct, st, cp, sp);
}

__device__ __forceinline__ void rot_pair(const float4 q,
                                         float& ur, float& ui,
                                         float& wr, float& wi) {
    // q = (ct, st, cp, sp)
    float ar = fmaf(-q.y, wr, q.x * ur);   // ct*u - st*v (real part)
    float ai = fmaf(-q.y, wi, q.x * ui);
    float br = fmaf( q.x, wr, q.y * ur);   // st*u + ct*v
    float bi = fmaf( q.x, wi, q.y * ui);
    ur = fmaf(-q.w, ai, q.z * ar);         // e^{i phi} * a
    ui = fmaf( q.w, ar, q.z * ai);
    wr = br;
    wi = bi;
}

// NOTE (R3 post-mortem, prior session): do NOT add min-waves=4 to launch_bounds.
// (256,4) capped VGPRs at 128 -> state shuffled through extra moves -> 526us.
//
// R(this): register ping-pong prefetch of coef one layer ahead. At VGPR=76 the
// compiler kept load-use distance ~0 inside each layer -> ~200cy L2 stall per
// j-group, VALUBusy 62%. Explicit NA/NB arrays force the prefetch registers;
// sched_barrier(0) after the load batch stops the scheduler sinking loads back
// to their uses to save registers.
__global__ __launch_bounds__(256, 2) void eunn_main_kernel(
    const float* __restrict__ x,
    const float4* __restrict__ coef,
    float* __restrict__ out) {
    const int lane = threadIdx.x & 63;
    const int wave = threadIdx.x >> 6;
    const int row0 = (blockIdx.x * 4 + wave) * RPW;
    const int lnext = (lane + 1) & 63;
    const int lprev = (lane + 63) & 63;

    // lane owns complex elements [16*lane, 16*lane+16) of each of its RPW rows
    float vr[RPW][16], vi[RPW][16];

#pragma unroll
    for (int r = 0; r < RPW; ++r) {
        const float4* src = (const float4*)(x + (size_t)(row0 + r) * (H_DIM * 2)) + lane * 8;
#pragma unroll
        for (int m = 0; m < 8; ++m) {
            float4 f = src[m];
            vr[r][2 * m]     = f.x; vi[r][2 * m]     = f.y;
            vr[r][2 * m + 1] = f.z; vi[r][2 * m + 1] = f.w;
        }
    }

    const float4* cl = coef + lane;   // lane-offset base

    // Ping-pong coef buffers: A/B hold the current layer (phase A / phase B),
    // NA/NB are being filled for the next layer. All indexing compile-time.
    float4 A[8], B[8], NA[8], NB[8];
#pragma unroll
    for (int j = 0; j < 8; ++j) {
        A[j] = cl[j * 64];
        B[j] = cl[(8 + j) * 64];
    }

    // One layer of compute using CUR_ coefs, prefetching layer `cnext` into NXT_.
#define EUNN_LAYER(A_, B_, NA_, NB_, cnext)                                          \
    do {                                                                             \
        const float4* cn_ = cl + (size_t)(cnext) * 1024;                             \
        float4 qq = B_[7];           /* phase-B boundary coef: already in regs */    \
        float qpx = __shfl(qq.x, lprev);   /* prev lane's ct' */                     \
        float qpy = __shfl(qq.y, lprev);   /* prev lane's st' */                     \
        /* phase A boundary-adjacent pairs first (j=0, j=7) */                       \
        _Pragma("unroll")                                                            \
        for (int r = 0; r < RPW; ++r) {                                              \
            rot_pair(A_[0], vr[r][0],  vi[r][0],  vr[r][1],  vi[r][1]);              \
            rot_pair(A_[7], vr[r][14], vi[r][14], vr[r][15], vi[r][15]);             \
        }                                                                            \
        float nbr[RPW], nbi[RPW], pbr[RPW], pbi[RPW];                                \
        _Pragma("unroll")                                                            \
        for (int r = 0; r < RPW; ++r) {                                              \
            nbr[r] = __shfl(vr[r][0],  lnext);   /* next lane's elem0 */             \
            nbi[r] = __shfl(vi[r][0],  lnext);                                       \
            pbr[r] = __shfl(vr[r][15], lprev);   /* prev lane's elem15 */            \
            pbi[r] = __shfl(vi[r][15], lprev);                                       \
        }                                                                            \
        /* prefetch next layer: phase A coefs + next qq (B[7], needed at top) */     \
        _Pragma("unroll")                                                            \
        for (int j = 0; j < 8; ++j) { NA_[j] = cn_[j * 64]; }                        \
        NB_[7] = cn_[15 * 64];                                                       \
        /* phase A remaining pairs j=1..6 */                                         \
        _Pragma("unroll")                                                            \
        for (int j = 1; j < 7; ++j) {                                                \
            _Pragma("unroll")                                                        \
            for (int r = 0; r < RPW; ++r)                                            \
                rot_pair(A_[j], vr[r][2 * j],     vi[r][2 * j],                      \
                                vr[r][2 * j + 1], vi[r][2 * j + 1]);                 \
        }                                                                            \
        /* prefetch next layer: phase B internal coefs */                            \
        _Pragma("unroll")                                                            \
        for (int j = 0; j < 7; ++j) { NB_[j] = cn_[(8 + j) * 64]; }                  \
        /* pin prefetch issues before phase-B compute (don't let the scheduler  */   \
        /* sink them back toward their uses to reduce pressure)                 */   \
        __builtin_amdgcn_sched_barrier(0);                                           \
        /* phase B internal pairs (local 2j+1, 2j+2), j=0..6 */                      \
        _Pragma("unroll")                                                            \
        for (int j = 0; j < 7; ++j) {                                                \
            _Pragma("unroll")                                                        \
            for (int r = 0; r < RPW; ++r)                                            \
                rot_pair(B_[j], vr[r][2 * j + 1], vi[r][2 * j + 1],                  \
                                vr[r][2 * j + 2], vi[r][2 * j + 2]);                 \
        }                                                                            \
        /* phase B boundary pair (my elem15, next lane's elem0) */                   \
        _Pragma("unroll")                                                            \
        for (int r = 0; r < RPW; ++r) {                                              \
            float ar = fmaf(-qq.y, nbr[r], qq.x * vr[r][15]);                        \
            float ai = fmaf(-qq.y, nbi[r], qq.x * vi[r][15]);                        \
            vr[r][15] = fmaf(-qq.w, ai, qq.z * ar);                                  \
            vi[r][15] = fmaf( qq.w, ar, qq.z * ai);                                  \
            float b0r = fmaf(qpx, vr[r][0], qpy * pbr[r]);                           \
            float b0i = fmaf(qpx, vi[r][0], qpy * pbi[r]);                           \
            vr[r][0] = b0r; vi[r][0] = b0i;                                          \
        }                                                                            \
    } while (0)

#pragma unroll 1
    for (int c = 0; c < C2; c += 2) {
        const int c1  = c + 1;                      // always < C2
        const int c2n = (c + 2 < C2) ? (c + 2) : 0; // last prefetch: dummy (layer 0)
        EUNN_LAYER(A, B, NA, NB, c1);
        EUNN_LAYER(NA, NB, A, B, c2n);
    }
#undef EUNN_LAYER

#pragma unroll
    for (int r = 0; r < RPW; ++r) {
        float4* dst = (float4*)(out + (size_t)(row0 + r) * (H_DIM * 2)) + lane * 8;
#pragma unroll
        for (int m = 0; m < 8; ++m) {
            dst[m] = make_float4(vr[r][2 * m],     vi[r][2 * m],
                                 vr[r][2 * m + 1], vi[r][2 * m + 1]);
        }
    }
}

extern "C" void kernel_launch(void* const* d_in, const int* in_sizes, int n_in,
                              void* d_out, int out_size, void* d_ws, size_t ws_size,
                              hipStream_t stream) {
    const float* x      = (const float*)d_in[0];
    const float* phi0   = (const float*)d_in[1];
    const float* theta0 = (const float*)d_in[2];
    const float* phi1   = (const float*)d_in[3];
    const float* theta1 = (const float*)d_in[4];
    float* out = (float*)d_out;
    float4* coef = (float4*)d_ws;   // 256*1024 float4 = 4 MB

    // coefficients: 256 layers * 2 phases * 512 pairs = 262144 threads
    hipLaunchKernelGGL(eunn_coef_kernel, dim3(1024), dim3(256), 0, stream,
                       phi0, theta0, phi1, theta1, coef);

    // main: 4096 rows / (4 waves/block * RPW rows/wave) = 512 blocks
    hipLaunchKernelGGL(eunn_main_kernel, dim3(512), dim3(256), 0, stream,
                       x, coef, out);
}

// Round 2
// 438.191 us; speedup vs baseline: 2.0586x; 2.0586x over previous
//
#include <hip/hip_runtime.h>

// EUNN: 256 layers; each layer = rotation on even pairs (2i,2i+1), then
// rotation on odd pairs (2i+1,2i+2 mod H).
// Pair math: y0 = e^{i*phi} (ct*u - st*v); y1 = st*u + ct*v.

#define H_DIM 1024
#define C2 256
#define RPW 2   // batch rows per wave

// coef layout: [c][phase][j][lane] as float4 (ct, st, cp, sp), pair i = 8*lane + j
// -> flat float4 index: ((c*2 + phase)*8 + j)*64 + lane,  4 MB total.
// For fixed c this is 1024 contiguous float4 = 16 KB -> one LDS stage per layer.

__global__ __launch_bounds__(256) void eunn_coef_kernel(
    const float* __restrict__ phi0, const float* __restrict__ theta0,
    const float* __restrict__ phi1, const float* __restrict__ theta1,
    float4* __restrict__ coef) {
    int t = blockIdx.x * 256 + threadIdx.x;     // [0, 256*2*512)
    int i = t & 511;                            // pair index
    int p = (t >> 9) & 1;                       // phase (0: even pairs, 1: odd pairs)
    int c = t >> 10;                            // layer
    const float* phi   = p ? phi1   : phi0;
    const float* theta = p ? theta1 : theta0;
    float ph = phi[i * C2 + c];
    float th = theta[i * C2 + c];
    float sp, cp, st, ct;
    __sincosf(ph, &sp, &cp);
    __sincosf(th, &st, &ct);
    int j = i & 7;
    int l = i >> 3;
    coef[(((c * 2 + p) * 8) + j) * 64 + l] = make_float4(ct, st, cp, sp);
}

__device__ __forceinline__ void rot_pair(const float4 q,
                                         float& ur, float& ui,
                                         float& wr, float& wi) {
    // q = (ct, st, cp, sp)
    float ar = fmaf(-q.y, wr, q.x * ur);   // ct*u - st*v (real part)
    float ai = fmaf(-q.y, wi, q.x * ui);
    float br = fmaf( q.x, wr, q.y * ur);   // st*u + ct*v
    float bi = fmaf( q.x, wi, q.y * ui);
    ur = fmaf(-q.w, ai, q.z * ar);         // e^{i phi} * a
    ui = fmaf( q.w, ar, q.z * ai);
    wr = br;
    wi = bi;
}

// NOTE (R3 post-mortem, prior session): do NOT add min-waves=4 to launch_bounds
// with big register demand -> spill. NOTE (R1 this session): register ping-pong
// prefetch (4x float4[8]) demanded ~200 VGPR, allocator capped at 128, spilled
// coefs to scratch -> WRITE_SIZE 33MB->1.66GB, 902us. Registers can't hold a
// prefetched layer; LDS can, at zero VGPR cost via global_load_lds DMA.
//
// R2: per-layer LDS double-buffered coef staging. All 4 waves/block read the
// SAME 16KB coef block per layer -> stage once per block (4x L2-traffic cut,
// 8.4GB->2.1GB) and read via ds_read_b128. Staging for layer c+1 issued at top
// of layer c; the implicit vmcnt(0) drain at the end-of-layer __syncthreads
// lands ~800cy after issue, so DMA latency is fully hidden.
__global__ __launch_bounds__(256, 2) void eunn_main_kernel(
    const float* __restrict__ x,
    const float4* __restrict__ coef,
    float* __restrict__ out) {
    const int lane = threadIdx.x & 63;
    const int wave = threadIdx.x >> 6;
    const int row0 = (blockIdx.x * 4 + wave) * RPW;
    const int lnext = (lane + 1) & 63;
    const int lprev = (lane + 63) & 63;

    __shared__ float4 cbuf[2][1024];   // [buf][j*64 + lane], 32 KB total

    // lane owns complex elements [16*lane, 16*lane+16) of each of its RPW rows
    float vr[RPW][16], vi[RPW][16];

#pragma unroll
    for (int r = 0; r < RPW; ++r) {
        const float4* src = (const float4*)(x + (size_t)(row0 + r) * (H_DIM * 2)) + lane * 8;
#pragma unroll
        for (int m = 0; m < 8; ++m) {
            float4 f = src[m];
            vr[r][2 * m]     = f.x; vi[r][2 * m]     = f.y;
            vr[r][2 * m + 1] = f.z; vi[r][2 * m + 1] = f.w;
        }
    }

    // Stage one 16KB layer block: 4 waves x 4 issues x (64 lanes x 16B).
    // global src is per-lane; LDS dest is wave-uniform base + lane*16 (HW rule).
#define STAGE(buf_, c_)                                                          \
    do {                                                                         \
        const float4* gsrc_ = coef + (size_t)(c_) * 1024 + wave * 256 + lane;    \
        float4* ldst_ = &cbuf[buf_][wave * 256];                                 \
        _Pragma("unroll")                                                        \
        for (int k_ = 0; k_ < 4; ++k_) {                                         \
            __builtin_amdgcn_global_load_lds(                                    \
                (const __attribute__((address_space(1))) void*)(gsrc_ + k_ * 64),\
                (__attribute__((address_space(3))) void*)(ldst_ + k_ * 64),      \
                16, 0, 0);                                                       \
        }                                                                        \
    } while (0)

    STAGE(0, 0);
    __syncthreads();   // compiler emits vmcnt(0) drain before s_barrier

#pragma unroll 1
    for (int c = 0; c < C2; ++c) {
        const int cur = c & 1;
        if (c + 1 < C2) STAGE(cur ^ 1, c + 1);   // issue next-layer DMA early

        const float4* cb = &cbuf[cur][lane];     // ds_read base; cb[j*64]

        // boundary coef for phase B, read up front; prev-lane copy via shuffle.
        float4 qq = cb[15 * 64];
        float qpx = __shfl(qq.x, lprev);   // prev lane's ct'
        float qpy = __shfl(qq.y, lprev);   // prev lane's st'

        // --- phase A, boundary-adjacent pairs first (j=0 and j=7) so the
        // cross-lane shuffles can issue early and hide under the FMA work.
        {
            float4 q0 = cb[0 * 64];
            float4 q7 = cb[7 * 64];
#pragma unroll
            for (int r = 0; r < RPW; ++r) {
                rot_pair(q0, vr[r][0],  vi[r][0],  vr[r][1],  vi[r][1]);
                rot_pair(q7, vr[r][14], vi[r][14], vr[r][15], vi[r][15]);
            }
        }
        // post-phase-A elem0 / elem15 are the inputs to the phase-B
        // boundary pair; grab neighbors now.
        float nbr[RPW], nbi[RPW], pbr[RPW], pbi[RPW];
#pragma unroll
        for (int r = 0; r < RPW; ++r) {
            nbr[r] = __shfl(vr[r][0],  lnext);   // next lane's elem0
            nbi[r] = __shfl(vi[r][0],  lnext);
            pbr[r] = __shfl(vr[r][15], lprev);   // prev lane's elem15
            pbi[r] = __shfl(vi[r][15], lprev);
        }

        // --- phase A remaining pairs j=1..6
#pragma unroll
        for (int j = 1; j < 7; ++j) {
            float4 q = cb[j * 64];
#pragma unroll
            for (int r = 0; r < RPW; ++r) {
                rot_pair(q, vr[r][2 * j],     vi[r][2 * j],
                            vr[r][2 * j + 1], vi[r][2 * j + 1]);
            }
        }

        // --- phase B internal pairs (local 2j+1, 2j+2), j=0..6
#pragma unroll
        for (int j = 0; j < 7; ++j) {
            float4 q = cb[(8 + j) * 64];
#pragma unroll
            for (int r = 0; r < RPW; ++r) {
                rot_pair(q, vr[r][2 * j + 1], vi[r][2 * j + 1],
                            vr[r][2 * j + 2], vi[r][2 * j + 2]);
            }
        }

        // --- phase B boundary pair (my elem15, next lane's elem0): both
        // sides computed locally from the pre-issued shuffles.
#pragma unroll
        for (int r = 0; r < RPW; ++r) {
            // new elem15 = e^{i phi}(ct*e15 - st*next_e0)
            float ar = fmaf(-qq.y, nbr[r], qq.x * vr[r][15]);
            float ai = fmaf(-qq.y, nbi[r], qq.x * vi[r][15]);
            vr[r][15] = fmaf(-qq.w, ai, qq.z * ar);
            vi[r][15] = fmaf( qq.w, ar, qq.z * ai);
            // new elem0 = st'*prev_e15 + ct'*e0  (lane-1's pair, second row)
            float b0r = fmaf(qpx, vr[r][0], qpy * pbr[r]);
            float b0i = fmaf(qpx, vi[r][0], qpy * pbi[r]);
            vr[r][0] = b0r; vi[r][0] = b0i;
        }

        // One barrier per layer: guarantees (a) next-layer DMA complete,
        // (b) all waves done reading cbuf[cur] before it's overwritten next iter.
        __syncthreads();
    }
#undef STAGE

#pragma unroll
    for (int r = 0; r < RPW; ++r) {
        float4* dst = (float4*)(out + (size_t)(row0 + r) * (H_DIM * 2)) + lane * 8;
#pragma unroll
        for (int m = 0; m < 8; ++m) {
            dst[m] = make_float4(vr[r][2 * m],     vi[r][2 * m],
                                 vr[r][2 * m + 1], vi[r][2 * m + 1]);
        }
    }
}

extern "C" void kernel_launch(void* const* d_in, const int* in_sizes, int n_in,
                              void* d_out, int out_size, void* d_ws, size_t ws_size,
                              hipStream_t stream) {
    const float* x      = (const float*)d_in[0];
    const float* phi0   = (const float*)d_in[1];
    const float* theta0 = (const float*)d_in[2];
    const float* phi1   = (const float*)d_in[3];
    const float* theta1 = (const float*)d_in[4];
    float* out = (float*)d_out;
    float4* coef = (float4*)d_ws;   // 256*1024 float4 = 4 MB

    // coefficients: 256 layers * 2 phases * 512 pairs = 262144 threads
    hipLaunchKernelGGL(eunn_coef_kernel, dim3(1024), dim3(256), 0, stream,
                       phi0, theta0, phi1, theta1, coef);

    // main: 4096 rows / (4 waves/block * RPW rows/wave) = 512 blocks
    hipLaunchKernelGGL(eunn_main_kernel, dim3(512), dim3(256), 0, stream,
                       x, coef, out);
}